// Round 11
// baseline (72.161 us; speedup 1.0000x reference)
//
#include <hip/hip_runtime.h>
#include <math.h>

#define N_IMG 512
#define N_ANGLES 25
#define N_DET 512
#define DET_SPACING 3.0f
#define SRC_DIST 512.0f
#define DET_DIST 512.0f
#define N_SAMPLES 1024

// ---------------------------------------------------------------------------
// ws layout: 4 MB of 2x2-BLOCKED quads.
//   quad(r,c) = { img[r][c], img[r][c+1], img[r+1][c], img[r+1][c+1] }
//   index = ((r>>1)<<10) + ((c>>1)<<2) + ((r&1)<<1) + (c&1)
// One 64 B line = a 2x2-pixel patch -> line reuse for any ray orientation.
// ---------------------------------------------------------------------------
__device__ __forceinline__ int quad_index(int r, int c) {
    return ((r >> 1) << 10) + ((c >> 1) << 2) + ((r & 1) << 1) + (c & 1);
}

__global__ __launch_bounds__(256) void build_quads(const float* __restrict__ img,
                                                   float4* __restrict__ quad) {
    int idx = blockIdx.x * blockDim.x + threadIdx.x;   // 0 .. 512*512-1
    int r = idx >> 9, c = idx & 511;
    int r1 = min(r + 1, N_IMG - 1);
    int c1 = min(c + 1, N_IMG - 1);
    float4 q;
    q.x = img[(r  << 9) + c ];
    q.y = img[(r  << 9) + c1];
    q.z = img[(r1 << 9) + c ];
    q.w = img[(r1 << 9) + c1];
    quad[quad_index(r, c)] = q;
}

// Reference-exact masked bilinear sample (boundary bands only).
__device__ __forceinline__ float masked_sample(const float* __restrict__ img,
                                               float col, float row) {
    float rf = floorf(row), cf = floorf(col);
    float fr = row - rf,    fc = col - cf;
    int r0 = (int)rf, c0 = (int)cf;
    float wr0 = (r0 >=  0 && r0 < N_IMG)     ? (1.0f - fr) : 0.0f;
    float wr1 = (r0 >= -1 && r0 < N_IMG - 1) ? fr          : 0.0f;
    float wc0 = (c0 >=  0 && c0 < N_IMG)     ? (1.0f - fc) : 0.0f;
    float wc1 = (c0 >= -1 && c0 < N_IMG - 1) ? fc          : 0.0f;
    int rc0 = min(max(r0,     0), N_IMG - 1);
    int rc1 = min(max(r0 + 1, 0), N_IMG - 1);
    int cc0 = min(max(c0,     0), N_IMG - 1);
    int cc1 = min(max(c0 + 1, 0), N_IMG - 1);
    float v00 = img[(rc0 << 9) + cc0];
    float v01 = img[(rc0 << 9) + cc1];
    float v10 = img[(rc1 << 9) + cc0];
    float v11 = img[(rc1 << 9) + cc1];
    return wr0 * (wc0 * v00 + wc1 * v01) + wr1 * (wc0 * v10 + wc1 * v11);
}

// Clip [tlo,thi] to { t : lo <= v0 + t*dv <= hi }.
__device__ __forceinline__ void slab(float v0, float dv, float lo, float hi,
                                     float& tlo, float& thi) {
    if (fabsf(dv) < 1e-8f) {
        if (v0 < lo || v0 > hi) { tlo = 1.0f; thi = 0.0f; }   // empty
    } else {
        float inv = 1.0f / dv;
        float ta = (lo - v0) * inv;
        float tb = (hi - v0) * inv;
        tlo = fmaxf(tlo, fminf(ta, tb));
        thi = fminf(thi, fmaxf(ta, tb));
    }
}

// 4 rays per wave, 16 lanes per ray: per-wave fixed cost (geometry, clip,
// reduction, store) amortized 4x — it was ~half the R9 kernel time at one
// wave per ray (12800 waves x ~500 cyc fixed overhead).
__global__ __launch_bounds__(256) void fanbeam_kernel(const float* __restrict__ img,
                                                      const float4* __restrict__ quad,
                                                      float* __restrict__ out) {
    const int tid = blockIdx.x * 256 + (int)threadIdx.x;   // 0 .. 204799
    const int ray = tid >> 4;                              // 16 lanes per ray
    const int sub = tid & 15;                              // lane within ray
    if (ray >= N_ANGLES * N_DET) return;

    const int a = ray >> 9;        // 512 dets per angle
    const int d = ray & 511;

    // f32 trig (error ~1e-7 rad -> ~6e-5 px; validated in R8/R9).
    float beta = (2.0f * (float)a / 25.0f) * 3.14159265358979323846f;
    float c, s;
    __sincosf(beta, &s, &c);
    float t = ((float)d - (N_DET - 1) * 0.5f) * DET_SPACING;
    float srcx = -SRC_DIST * s;
    float srcy =  SRC_DIST * c;
    float dx = (t * c + DET_DIST * s) - srcx;
    float dy = (t * s - DET_DIST * c) - srcy;
    float seg = sqrtf(dx * dx + dy * dy);

    const float half = (N_IMG - 1) * 0.5f;   // 255.5
    const float col0 = srcx + half;
    const float row0 = half - srcy;
    const float drow = -dy;
    const float inv_n = 1.0f / N_SAMPLES;

    // Outer window: outside col/row in (-1, 512) every corner weight is 0.
    float tA = 0.0f, tB = 1.0f;
    slab(col0, dx,   -1.01f, 512.01f, tA, tB);
    slab(row0, drow, -1.01f, 512.01f, tA, tB);
    int i_lo, i_hi;
    if (tB < tA) { i_lo = 1; i_hi = 0; }
    else {
        i_lo = max(0,             (int)floorf(tA * N_SAMPLES - 0.5f) - 1);
        i_hi = min(N_SAMPLES - 1, (int)ceilf (tB * N_SAMPLES - 0.5f) + 1);
    }

    // Interior window: col,row in [0.01, 510.99] -> all four corners valid.
    float tC = 0.0f, tD = 1.0f;
    slab(col0, dx,   0.01f, 510.99f, tC, tD);
    slab(row0, drow, 0.01f, 510.99f, tC, tD);
    int j_lo, j_hi;
    if (tD < tC) { j_lo = 1; j_hi = 0; }
    else {
        j_lo = (int)ceilf (tC * N_SAMPLES - 0.5f) + 1;
        j_hi = (int)floorf(tD * N_SAMPLES - 0.5f) - 1;
    }
    j_lo = max(j_lo, i_lo);
    j_hi = min(j_hi, i_hi);
    if (j_lo > j_hi) {            // no interior stretch: everything masked
        j_lo = i_hi + 1;
        j_hi = i_hi;
    }

    float acc = 0.0f;

    // Leading masked band: [i_lo, j_lo-1]   (per-lane bounds; adjacent rays
    // have near-identical windows, so intra-wave divergence is negligible).
    for (int i = i_lo + sub; i < j_lo; i += 16) {
        float ts  = ((float)i + 0.5f) * inv_n;
        acc += masked_sample(img, fmaf(ts, dx, col0), fmaf(ts, drow, row0));
    }
    // Interior fast path: ONE 16 B gather per sample.
    #pragma unroll 2
    for (int i = j_lo + sub; i <= j_hi; i += 16) {
        float ts  = ((float)i + 0.5f) * inv_n;
        float col = fmaf(ts, dx,   col0);
        float row = fmaf(ts, drow, row0);
        float cf = floorf(col), rf = floorf(row);
        float fc = col - cf,    fr = row - rf;
        int ci = min(max((int)cf, 0), N_IMG - 2);
        int ri = min(max((int)rf, 0), N_IMG - 2);
        float4 q = quad[quad_index(ri, ci)];
        float top = fmaf(fc, q.y - q.x, q.x);
        float bot = fmaf(fc, q.w - q.z, q.z);
        acc += fmaf(fr, bot - top, top);
    }
    // Trailing masked band: [max(j_hi+1, i_lo), i_hi].
    for (int i = max(j_hi + 1, i_lo) + sub; i <= i_hi; i += 16) {
        float ts  = ((float)i + 0.5f) * inv_n;
        acc += masked_sample(img, fmaf(ts, dx, col0), fmaf(ts, drow, row0));
    }

    // Reduce within each 16-lane ray group (4 steps instead of 6).
    #pragma unroll
    for (int off = 8; off > 0; off >>= 1)
        acc += __shfl_down(acc, off, 16);

    if (sub == 0) out[ray] = acc * (seg * inv_n);
}

extern "C" void kernel_launch(void* const* d_in, const int* in_sizes, int n_in,
                              void* d_out, int out_size, void* d_ws, size_t ws_size,
                              hipStream_t stream) {
    const float* img = (const float*)d_in[0];
    float* out = (float*)d_out;
    float4* quad = (float4*)d_ws;                      // 512*512*16 B = 4 MB

    build_quads<<<(N_IMG * N_IMG) / 256, 256, 0, stream>>>(img, quad);

    const int n_rays = N_ANGLES * N_DET;               // 12800
    // 16 rays per 256-thread block (4 waves x 4 rays) -> 800 blocks.
    const int blocks = n_rays / 16;
    fanbeam_kernel<<<blocks, 256, 0, stream>>>(img, quad, out);
}

// Round 12
// 71.117 us; speedup vs baseline: 1.0147x; 1.0147x over previous
//
#include <hip/hip_runtime.h>
#include <math.h>

#define N_IMG 512
#define N_ANGLES 25
#define N_DET 512
#define DET_SPACING 3.0f
#define SRC_DIST 512.0f
#define DET_DIST 512.0f
#define N_SAMPLES 1024
#define QP 258            // quad patches per side (covers r,c in [-2, 513])

// ---------------------------------------------------------------------------
// ws: 4.26 MB padded, 2x2-blocked quad array.
//   quad(r,c) = {v(r,c), v(r,c+1), v(r+1,c), v(r+1,c+1)},  v = img inside,
//   0 outside  ->  bilinear on quads == reference's per-corner masking, with
//   NO masked path needed anywhere (r,c in [-2,513]; patches at the rim are
//   all-zero, so the batch tail can redirect dead lanes to patch 0 = zeros).
//   index: R=r+2, C=c+2 in [0,515];  ((R>>1)*258 + (C>>1))*4 + (R&1)*2+(C&1)
//   One 64 B line = 2x2 pixels -> line reuse for any ray orientation.
// ---------------------------------------------------------------------------
__device__ __forceinline__ int quad_idx(int R, int C) {
    return ((((R >> 1) * QP) + (C >> 1)) << 2) + ((R & 1) << 1) + (C & 1);
}

__device__ __forceinline__ float img_at(const float* __restrict__ img, int r, int c) {
    return ((unsigned)r < N_IMG && (unsigned)c < N_IMG) ? img[(r << 9) + c] : 0.0f;
}

__global__ __launch_bounds__(256) void build_quads(const float* __restrict__ img,
                                                   float4* __restrict__ quad) {
    int idx = blockIdx.x * 256 + (int)threadIdx.x;     // covers R,C in [0,515]
    if (idx >= 516 * 516) return;
    int R = idx / 516, C = idx - R * 516;
    int r = R - 2, c = C - 2;
    float4 q;
    q.x = img_at(img, r,     c);
    q.y = img_at(img, r,     c + 1);
    q.z = img_at(img, r + 1, c);
    q.w = img_at(img, r + 1, c + 1);
    quad[quad_idx(R, C)] = q;
}

// Clip [tlo,thi] to { t : lo <= v0 + t*dv <= hi }.
__device__ __forceinline__ void slab(float v0, float dv, float lo, float hi,
                                     float& tlo, float& thi) {
    if (fabsf(dv) < 1e-8f) {
        if (v0 < lo || v0 > hi) { tlo = 1.0f; thi = 0.0f; }
    } else {
        float inv = 1.0f / dv;
        float ta = (lo - v0) * inv;
        float tb = (hi - v0) * inv;
        tlo = fmaxf(tlo, fminf(ta, tb));
        thi = fminf(thi, fmaxf(ta, tb));
    }
}

__device__ __forceinline__ void sample_addr(float col0, float dx, float row0,
                                            float drow, int i,
                                            int& idx, float& fc, float& fr) {
    float ts  = ((float)i + 0.5f) * (1.0f / N_SAMPLES);
    float col = fmaf(ts, dx,   col0);
    float row = fmaf(ts, drow, row0);
    float cf = floorf(col), rf = floorf(row);
    fc = col - cf;  fr = row - rf;
    int Ci = min(max((int)cf + 2, 0), 514);   // clamps bind only for tail
    int Ri = min(max((int)rf + 2, 0), 514);   // overshoot samples (zeroed)
    idx = quad_idx(Ri, Ci);
}

__device__ __forceinline__ float bil(float4 q, float fc, float fr) {
    float top = fmaf(fc, q.y - q.x, q.x);
    float bot = fmaf(fc, q.w - q.z, q.z);
    return fmaf(fr, bot - top, top);
}

// One wave per ray (12800 waves ~ 8/SIMD), 4-deep manual load batching for
// memory-level parallelism — the R6..R11 plateau at ~24 us is exposed L2
// latency (~200 cyc/iter, trip counts 5..9, unroll-2 only).
__global__ __launch_bounds__(256) void fanbeam_kernel(const float4* __restrict__ quad,
                                                      float* __restrict__ out) {
    const int gid  = blockIdx.x * 256 + (int)threadIdx.x;
    const int ray  = gid >> 6;
    const int lane = (int)threadIdx.x & 63;
    if (ray >= N_ANGLES * N_DET) return;

    const int a = ray >> 9;
    const int d = ray & 511;

    float beta = (2.0f * (float)a / 25.0f) * 3.14159265358979323846f;
    float c, s;
    __sincosf(beta, &s, &c);
    float t = ((float)d - (N_DET - 1) * 0.5f) * DET_SPACING;
    float srcx = -SRC_DIST * s;
    float srcy =  SRC_DIST * c;
    float dx = (t * c + DET_DIST * s) - srcx;
    float dy = (t * s - DET_DIST * c) - srcy;
    float seg = sqrtf(dx * dx + dy * dy);

    const float half = (N_IMG - 1) * 0.5f;
    const float col0 = srcx + half;
    const float row0 = half - srcy;
    const float drow = -dy;

    // Single outer window: outside col,row in (-1,512) everything is 0, and
    // the padded quads make every in-window sample a plain bilinear.
    float tA = 0.0f, tB = 1.0f;
    slab(col0, dx,   -1.01f, 512.01f, tA, tB);
    slab(row0, drow, -1.01f, 512.01f, tA, tB);

    float acc = 0.0f;
    if (tA <= tB) {
        int i_lo = max(0,             (int)floorf(tA * N_SAMPLES - 0.5f) - 1);
        int i_hi = min(N_SAMPLES - 1, (int)ceilf (tB * N_SAMPLES - 0.5f) + 1);
        int n = i_hi - i_lo + 1;                        // wave-uniform
        int k = 0;
        // Full 4-deep batches: 4 independent loads in flight per lane.
        for (; k + 256 <= n; k += 256) {
            int i0 = i_lo + k + lane;
            int x0, x1, x2, x3; float a0,a1,a2,a3,b0,b1,b2,b3;
            sample_addr(col0, dx, row0, drow, i0,       x0, a0, b0);
            sample_addr(col0, dx, row0, drow, i0 + 64,  x1, a1, b1);
            sample_addr(col0, dx, row0, drow, i0 + 128, x2, a2, b2);
            sample_addr(col0, dx, row0, drow, i0 + 192, x3, a3, b3);
            float4 q0 = quad[x0];
            float4 q1 = quad[x1];
            float4 q2 = quad[x2];
            float4 q3 = quad[x3];
            acc += bil(q0, a0, b0) + bil(q1, a1, b1)
                 + bil(q2, a2, b2) + bil(q3, a3, b3);
        }
        // Tail batch: dead samples redirected to patch(0,0) (all zeros) so
        // their contribution is exactly 0 — loop stays branch-free.
        if (k < n) {
            int i0 = i_lo + k + lane;
            int r0 = k + lane, rem = n;
            int x0, x1, x2, x3; float a0,a1,a2,a3,b0,b1,b2,b3;
            sample_addr(col0, dx, row0, drow, i0,       x0, a0, b0);
            sample_addr(col0, dx, row0, drow, i0 + 64,  x1, a1, b1);
            sample_addr(col0, dx, row0, drow, i0 + 128, x2, a2, b2);
            sample_addr(col0, dx, row0, drow, i0 + 192, x3, a3, b3);
            x0 = (r0       < rem) ? x0 : 0;
            x1 = (r0 + 64  < rem) ? x1 : 0;
            x2 = (r0 + 128 < rem) ? x2 : 0;
            x3 = (r0 + 192 < rem) ? x3 : 0;
            float4 q0 = quad[x0];
            float4 q1 = quad[x1];
            float4 q2 = quad[x2];
            float4 q3 = quad[x3];
            acc += bil(q0, a0, b0) + bil(q1, a1, b1)
                 + bil(q2, a2, b2) + bil(q3, a3, b3);
        }
    }

    #pragma unroll
    for (int off = 32; off > 0; off >>= 1)
        acc += __shfl_down(acc, off, 64);

    if (lane == 0) out[ray] = acc * (seg * (1.0f / N_SAMPLES));
}

extern "C" void kernel_launch(void* const* d_in, const int* in_sizes, int n_in,
                              void* d_out, int out_size, void* d_ws, size_t ws_size,
                              hipStream_t stream) {
    const float* img = (const float*)d_in[0];
    float* out = (float*)d_out;
    float4* quad = (float4*)d_ws;                  // 258*258*4*16 B = 4.26 MB

    build_quads<<<(516 * 516 + 255) / 256, 256, 0, stream>>>(img, quad);

    const int n_rays = N_ANGLES * N_DET;           // 12800, one wave each
    fanbeam_kernel<<<n_rays * 64 / 256, 256, 0, stream>>>(quad, out);
}